// Round 1
// baseline (101.022 us; speedup 1.0000x reference)
//
#include <hip/hip_runtime.h>
#include <hip/hip_bf16.h>

#define NSAMP 8192
#define HD 128
#define NC 18
#define SB 8            // samples per block
#define NCOLS 144       // SB*NC = 9 n-tiles of 16
#define KSTR 136        // padded k-stride in shorts (272B rows, 16B-aligned)

typedef __attribute__((ext_vector_type(8))) short bf16x8;
typedef __attribute__((ext_vector_type(4))) float f32x4;
typedef float f2 __attribute__((ext_vector_type(2)));

// Monomial map: 0:1 1:a 2:b 3:c 4:a2 5:ab 6:b2 7:ca 8:cb 9:a3 10:a2b 11:ab2
// 12:b3 13:ca2 14:cb2 15:a4 16:a2b2 17:b4   (a=dx, b=dy, c=dt)

__device__ __forceinline__ unsigned packf2(f2 v) {
    __hip_bfloat162 h = __float22bfloat162_rn(float2{v.x, v.y});
    return *(unsigned*)&h;
}
__device__ __forceinline__ f2 unpk(unsigned r) {
    f2 v;
    v.x = __uint_as_float(r << 16);
    v.y = __uint_as_float(r & 0xffff0000u);
    return v;
}

// R10: branchless fast tanh: 1 - 2*rcp(exp(2x)+1).
// v_exp_f32 + v_rcp_f32, ~6 instrs vs libm tanhf's ~25-40 with branches.
// rel err ~1e-6 << bf16 round-trip (4e-3); saturates exactly (rcp(inf)=0).
__device__ __forceinline__ f2 ftanh2(f2 v) {
    const float ex = __expf(v.x * 2.0f);
    const float ey = __expf(v.y * 2.0f);
    const float rx = __builtin_amdgcn_rcpf(ex + 1.0f);
    const float ry = __builtin_amdgcn_rcpf(ey + 1.0f);
    f2 r;
    r.x = 1.0f - (rx + rx);
    r.y = 1.0f - (ry + ry);
    return r;
}

// tanh jet: out = y + s*p + P*(t2 + t3*p + t4*P), P = p^2 (18-monomial trunc)
__device__ __forceinline__ void tanh_jet2(const f2* __restrict__ f,
                                          f2* __restrict__ out) {
    const f2 y = ftanh2(f[0]);
    const f2 one = {1.0f, 1.0f};
    const f2 s  = one - y*y;
    const f2 t2 = -y*s;
    const f2 t3 = s*(y*y - 0.3333333333333333f);
    const f2 t4 = y*s*(one + one - 3.0f*y*y) * 0.3333333333333333f;
    const f2 tp1 = f[1]+f[1], tp2 = f[2]+f[2], tp3 = f[3]+f[3], tp4 = f[4]+f[4];
    f2 P[18];
    P[4]  = f[1]*f[1];
    P[5]  = tp1*f[2];
    P[6]  = f[2]*f[2];
    P[7]  = tp1*f[3];
    P[8]  = tp2*f[3];
    P[9]  = tp1*f[4];
    P[10] = tp1*f[5]  + tp2*f[4];
    P[11] = tp1*f[6]  + tp2*f[5];
    P[12] = tp2*f[6];
    P[13] = tp1*f[7]  + tp3*f[4];
    P[14] = tp2*f[8]  + tp3*f[6];
    P[15] = tp1*f[9]  + f[4]*f[4];
    P[16] = tp1*f[11] + tp2*f[10] + tp4*f[6] + f[5]*f[5];
    P[17] = tp2*f[12] + f[6]*f[6];
    f2 q[18];
    q[0] = t2;
    q[1] = t3*f[1];  q[2] = t3*f[2];  q[3] = t3*f[3];
#pragma unroll
    for (int m = 4; m <= 17; ++m) q[m] = t3*f[m] + t4*P[m];
    out[0] = y;
    out[1] = s*f[1];  out[2] = s*f[2];  out[3] = s*f[3];
    out[4] = s*f[4]  + P[4]*q[0];
    out[5] = s*f[5]  + P[5]*q[0];
    out[6] = s*f[6]  + P[6]*q[0];
    out[7] = s*f[7]  + P[7]*q[0];
    out[8] = s*f[8]  + P[8]*q[0];
    out[9]  = s*f[9]  + P[9]*q[0]  + P[4]*q[1];
    out[10] = s*f[10] + P[10]*q[0] + P[5]*q[1] + P[4]*q[2];
    out[11] = s*f[11] + P[11]*q[0] + P[6]*q[1] + P[5]*q[2];
    out[12] = s*f[12] + P[12]*q[0] + P[6]*q[2];
    out[13] = s*f[13] + P[13]*q[0] + P[7]*q[1] + P[4]*q[3];
    out[14] = s*f[14] + P[14]*q[0] + P[8]*q[2] + P[6]*q[3];
    out[15] = s*f[15] + P[15]*q[0] + P[9]*q[1] + P[4]*q[4];
    out[16] = s*f[16] + P[16]*q[0] + P[11]*q[1] + P[10]*q[2]
            + P[4]*q[6] + P[6]*q[4] + P[5]*q[5];
    out[17] = s*f[17] + P[17]*q[0] + P[12]*q[2] + P[6]*q[6];
}

// Layer-1 jet: input jet is LINEAR (p1,p2,p3 only) -> fully sparse
__device__ __forceinline__ void tanh_jet_lin2(f2 f0, f2 p1, f2 p2, f2 p3,
                                              f2* __restrict__ out) {
    const f2 y = ftanh2(f0);
    const f2 one = {1.0f, 1.0f};
    const f2 s  = one - y*y;
    const f2 t2 = -y*s;
    const f2 t3 = s*(y*y - 0.3333333333333333f);
    const f2 t4 = y*s*(one + one - 3.0f*y*y) * 0.3333333333333333f;
    const f2 tp1 = p1+p1, tp2 = p2+p2;
    const f2 P4 = p1*p1, P5 = tp1*p2, P6 = p2*p2, P7 = tp1*p3, P8 = tp2*p3;
    const f2 q0 = t2;
    const f2 q1 = t3*p1, q2 = t3*p2, q3 = t3*p3;
    const f2 q4 = t4*P4, q5 = t4*P5, q6 = t4*P6;
    out[0] = y;
    out[1] = s*p1;  out[2] = s*p2;  out[3] = s*p3;
    out[4] = P4*q0; out[5] = P5*q0; out[6] = P6*q0;
    out[7] = P7*q0; out[8] = P8*q0;
    out[9]  = P4*q1;
    out[10] = P4*q2 + P5*q1;
    out[11] = P5*q2 + P6*q1;
    out[12] = P6*q2;
    out[13] = P4*q3 + P7*q1;
    out[14] = P6*q3 + P8*q2;
    out[15] = P4*q4;
    out[16] = P4*q6 + P6*q4 + P5*q5;
    out[17] = P6*q6;
}

// NOTES (measured across R4-R10):
// - __launch_bounds__ 2nd arg acts as a residency cap: (512,2) -> ~20% occ
//   (R6,R8 regressions). R10 pins (512,8): hard 64-VGPR cap so the A-frag
//   gather cannot silently inflate VGPR past 64 and halve occupancy.
// - VGPR=64 is load-bearing: 8 waves/SIMD x 4 blocks/CU needs <=64.
// - GEMM tiling wave=(1 m-tile x 9 n-tiles) beats 2x5 m-grouping by ~13us
//   (R5/R9 both regressed; bank conflicts 10x higher there).
// - R10: transpose_w kernel eliminated. Each wave gathers its 32 strided
//   fp32 weights (stride 512B, L2-hot: W2+W3 = 128KB << 4MB/XCD L2) and
//   packs to bf16 in-register. Saves one dependent dispatch (~4-6us).
// - R10: libm tanhf -> ftanh2 (exp+rcp, branchless) in all jet phases.
__global__ __launch_bounds__(512, 8)
void hydro_main(const float* __restrict__ x,
                const float* __restrict__ W1, const float* __restrict__ b1,
                const float* __restrict__ W2, const float* __restrict__ b2,
                const float* __restrict__ W3, const float* __restrict__ b3,
                const float* __restrict__ W4, const float* __restrict__ nu_p,
                float* __restrict__ out) {
    __shared__ __align__(16) unsigned short Hl[NCOLS * KSTR];  // jets/preacts, bf16
    __shared__ float psis[NCOLS];

    const int tid = threadIdx.x;
    const int wv  = tid >> 6;
    const int ln  = tid & 63;
    const int s0  = blockIdx.x * SB;
    const int s   = tid >> 6;          // sample slot 0..7
    const int jp  = tid & 63;          // unit pair 0..63

    // ---- Layer 1: 512 unit-pairs, sparse float2 jets ----
    {
        const float xs = x[3 * (s0 + s) + 0];
        const float ys = x[3 * (s0 + s) + 1];
        const float ts = x[3 * (s0 + s) + 2];
        const int j0 = 2 * jp;
        const f2 wx = *(const f2*)&W1[j0];
        const f2 wy = *(const f2*)&W1[HD + j0];
        const f2 wt = *(const f2*)&W1[2 * HD + j0];
        const f2 bb = *(const f2*)&b1[j0];
        f2 h[NC];
        const f2 fc = wx * xs + wy * ys + wt * ts + bb;
        tanh_jet_lin2(fc, wx, wy, wt, h);
#pragma unroll
        for (int c = 0; c < NC; ++c)
            *(unsigned*)&Hl[(s * NC + c) * KSTR + j0] = packf2(h[c]);
    }
    __syncthreads();

    // ---- Layers 2,3: MFMA GEMM (A gathered from global W, k-strided) + tanh ----
    const int lr   = ln & 15;
    const int koff = (ln >> 4) * 8;

#pragma unroll 1
    for (int L = 0; L < 2; ++L) {
        const float* __restrict__ Wg = L ? W3 : W2;
        // A-frags for m-tile wv: row j = wv*16+lr of W^T, i.e. column j of W.
        // 8 consecutive k per frag = 8 fp32 loads at stride HD*4B; pack pairs
        // to bf16 immediately to keep liveness low (under the 64-VGPR cap).
        bf16x8 Af[4];
#pragma unroll
        for (int ks = 0; ks < 4; ++ks) {
            const float* wp = &Wg[(ks * 32 + koff) * HD + (wv * 16 + lr)];
            const unsigned r0 = packf2(f2{wp[0 * HD], wp[1 * HD]});
            const unsigned r1 = packf2(f2{wp[2 * HD], wp[3 * HD]});
            const unsigned r2 = packf2(f2{wp[4 * HD], wp[5 * HD]});
            const unsigned r3 = packf2(f2{wp[6 * HD], wp[7 * HD]});
            const uint4 q{r0, r1, r2, r3};
            Af[ks] = *(const bf16x8*)&q;
        }
        f32x4 acc[9];
#pragma unroll
        for (int nt = 0; nt < 9; ++nt) acc[nt] = (f32x4)0.0f;
#pragma unroll
        for (int ks = 0; ks < 4; ++ks) {
#pragma unroll
            for (int nt = 0; nt < 9; ++nt) {
                const bf16x8 Bf = *(const bf16x8*)&Hl[(nt * 16 + lr) * KSTR + ks * 32 + koff];
                acc[nt] = __builtin_amdgcn_mfma_f32_16x16x32_bf16(Af[ks], Bf, acc[nt], 0, 0, 0);
            }
        }
        __syncthreads();
        // writeback pre-activations: C[m][n] -> Hl[n][m], bf16
#pragma unroll
        for (int nt = 0; nt < 9; ++nt) {
            const int n = nt * 16 + lr;
            const int m = wv * 16 + (ln >> 4) * 4;
            uint2 w;
            w.x = packf2(f2{acc[nt].x, acc[nt].y});
            w.y = packf2(f2{acc[nt].z, acc[nt].w});
            *(uint2*)&Hl[n * KSTR + m] = w;
        }
        __syncthreads();
        // tanh phase: ALL 512 threads, one f2-jet each, b32 LDS ops
        // (wave-uniform row + lane-contiguous dwords -> conflict-free)
        {
            const float* bL = L ? b3 : b2;
            const int j0 = 2 * jp;
            f2 fa[NC], ha[NC];
#pragma unroll
            for (int c = 0; c < NC; ++c)
                fa[c] = unpk(*(const unsigned*)&Hl[(s * NC + c) * KSTR + j0]);
            fa[0] += *(const f2*)&bL[j0];
            tanh_jet2(fa, ha);
#pragma unroll
            for (int c = 0; c < NC; ++c)
                *(unsigned*)&Hl[(s * NC + c) * KSTR + j0] = packf2(ha[c]);
        }
        __syncthreads();
    }

    // ---- Layer 4: psi jet coefs = W4 . h3 ----
    if (tid < NCOLS) {
        float acc = 0.0f;
#pragma unroll
        for (int kk = 0; kk < 16; ++kk) {
            const uint4 q = *(const uint4*)&Hl[tid * KSTR + kk * 8];
            const int k = kk * 8;
            const f2 e0 = unpk(q.x), e1 = unpk(q.y), e2 = unpk(q.z), e3 = unpk(q.w);
            acc = fmaf(e0.x, W4[k + 0], acc);
            acc = fmaf(e0.y, W4[k + 1], acc);
            acc = fmaf(e1.x, W4[k + 2], acc);
            acc = fmaf(e1.y, W4[k + 3], acc);
            acc = fmaf(e2.x, W4[k + 4], acc);
            acc = fmaf(e2.y, W4[k + 5], acc);
            acc = fmaf(e3.x, W4[k + 6], acc);
            acc = fmaf(e3.y, W4[k + 7], acc);
        }
        psis[tid] = acc;
    }
    __syncthreads();

    if (tid < SB) {
        const float* p = &psis[tid * NC];
        const float nu = nu_p[0];
        const float u  = p[2];
        const float v  = -p[1];
        const float wx = -(6.0f * p[9]  + 2.0f * p[11]);
        const float wy = -(2.0f * p[10] + 6.0f * p[12]);
        const float wt = -(2.0f * p[13] + 2.0f * p[14]);
        const float lapw = -(24.0f * p[15] + 8.0f * p[16] + 24.0f * p[17]);
        const float nse  = wt + wx * u + wy * v - nu * lapw;
        const int gi = s0 + tid;
        out[2 * gi]         = u;
        out[2 * gi + 1]     = v;
        out[2 * NSAMP + gi] = nse;
    }
}

extern "C" void kernel_launch(void* const* d_in, const int* in_sizes, int n_in,
                              void* d_out, int out_size, void* d_ws, size_t ws_size,
                              hipStream_t stream) {
    const float* x  = (const float*)d_in[0];
    const float* W1 = (const float*)d_in[1];
    const float* b1 = (const float*)d_in[2];
    const float* W2 = (const float*)d_in[3];
    const float* b2 = (const float*)d_in[4];
    const float* W3 = (const float*)d_in[5];
    const float* b3 = (const float*)d_in[6];
    const float* W4 = (const float*)d_in[7];
    const float* nu = (const float*)d_in[9];
    float* out = (float*)d_out;

    hipLaunchKernelGGL(hydro_main, dim3(NSAMP / SB), dim3(512), 0, stream,
                       x, W1, b1, W2, b2, W3, b3, W4, nu, out);
}